// Round 2
// 945.478 us; speedup vs baseline: 1.2039x; 1.2039x over previous
//
#include <hip/hip_runtime.h>
#include <hip/hip_bf16.h>
#include <math.h>

// Problem constants
#define N_ROWS 16384   // B*T
#define DIM    256
#define KC     4096
#define TOPK   3
#define KSPLIT 768     // [hi|hi|lo] x [hi|lo|hi] fp16-split K

// Output flat offsets (floats)
#define O_LOSS   0
#define O_QUANT  1
#define O_PERP   12582913
#define O_AVGP   12582914
#define O_IDX    12587010
#define O_DIST   12636162
#define O_NCS    79745026
#define O_NEMAW  79749122
#define O_UPD    80797698

typedef _Float16 h4_t __attribute__((ext_vector_type(4)));
typedef _Float16 h8_t __attribute__((ext_vector_type(8)));
typedef float    f4_t __attribute__((ext_vector_type(4)));

// async global->LDS, 16B per lane, wave-uniform LDS base + lane*16
#define GLL(g, l) __builtin_amdgcn_global_load_lds( \
    (const __attribute__((address_space(1))) unsigned int*)(g), \
    (__attribute__((address_space(3))) unsigned int*)(l), 16, 0, 0)

// ---------------------------------------------------------------- row norms
__global__ __launch_bounds__(256) void rownorm_kernel(
    const float* __restrict__ X, float* __restrict__ out, int rows)
{
    int wave = threadIdx.x >> 6;
    int lane = threadIdx.x & 63;
    int row  = blockIdx.x * 4 + wave;
    if (row >= rows) return;
    float4 v = *(const float4*)&X[(size_t)row * DIM + lane * 4];
    float s = v.x*v.x + v.y*v.y + v.z*v.z + v.w*v.w;
    #pragma unroll
    for (int off = 32; off; off >>= 1) s += __shfl_down(s, off);
    if (lane == 0) out[row] = s;
}

// -------------------------------------------- fp32 -> fp16 hi/lo split pack
// Q row layout (768): A: [hi | hi | lo]  (hi2_off=256, lo_off=512)
//                     B: [hi | lo | hi]  (hi2_off=512, lo_off=256)
__global__ __launch_bounds__(256) void convert_kernel(
    const float* __restrict__ X, _Float16* __restrict__ Q,
    int lo_off, int hi2_off)
{
    int wave = threadIdx.x >> 6;
    int lane = threadIdx.x & 63;
    int row  = blockIdx.x * 4 + wave;          // grid exact
    float4 v = *(const float4*)&X[(size_t)row * DIM + lane * 4];
    h4_t hi, lo;
    hi[0] = (_Float16)v.x; lo[0] = (_Float16)(v.x - (float)hi[0]);
    hi[1] = (_Float16)v.y; lo[1] = (_Float16)(v.y - (float)hi[1]);
    hi[2] = (_Float16)v.z; lo[2] = (_Float16)(v.z - (float)hi[2]);
    hi[3] = (_Float16)v.w; lo[3] = (_Float16)(v.w - (float)hi[3]);
    _Float16* q = Q + (size_t)row * KSPLIT + lane * 4;
    *(h4_t*)(q)           = hi;
    *(h4_t*)(q + hi2_off) = hi;
    *(h4_t*)(q + lo_off)  = lo;
}

// ------------------------------------------------- MFMA GEMM (fp16-split)
// dist[m,n] = xn[m] + en[n] - 2 * dot_f32(X[m,:], E[n,:])
// 128x128 tile, BK=64, 4 waves (2x2), 4x4 frags of 16x16x32 each.
__global__ __launch_bounds__(256) void gemm_dist_kernel(
    const _Float16* __restrict__ Aq,   // [N_ROWS, 768]
    const _Float16* __restrict__ Bq,   // [KC, 768]
    const float* __restrict__ xn,      // [N_ROWS]
    const float* __restrict__ en,      // [KC]
    float* __restrict__ dist)          // [N_ROWS, KC]
{
    __shared__ _Float16 As[128 * 64];
    __shared__ _Float16 Bs[128 * 64];

    // XCD-aware bijective swizzle: nwg=4096, 8 XCDs, 512 per chunk
    int bid = blockIdx.x;
    int swz = (bid & 7) * 512 + (bid >> 3);
    int m0 = (swz >> 5) * 128;     // 128 M-tiles
    int n0 = (swz & 31) * 128;     // 32  N-tiles

    const int tid = threadIdx.x;
    const int w = tid >> 6, l = tid & 63;
    const int wr = w >> 1, wc = w & 1;

    f4_t acc[4][4] = {};

    const int srow = l >> 3;              // 0..7 within 8-row chunk
    const int scol = (l & 7) * 8;         // half offset within row
    const _Float16* Abase = Aq + (size_t)m0 * KSPLIT;
    const _Float16* Bbase = Bq + (size_t)n0 * KSPLIT;

    for (int kt = 0; kt < KSPLIT; kt += 64) {
        #pragma unroll
        for (int i = 0; i < 4; i++) {
            int c = w * 4 + i;            // chunk 0..15, 8 rows each
            int rg = c * 8 + srow;
            GLL(Abase + (size_t)rg * KSPLIT + kt + scol, &As[c * 512]);
            GLL(Bbase + (size_t)rg * KSPLIT + kt + scol, &Bs[c * 512]);
        }
        __syncthreads();                  // drains vmcnt before barrier

        #pragma unroll
        for (int ks = 0; ks < 2; ks++) {
            h8_t a[4], b[4];
            #pragma unroll
            for (int mf = 0; mf < 4; mf++)
                a[mf] = *(const h8_t*)&As[(wr*64 + mf*16 + (l & 15)) * 64 + ks*32 + (l >> 4) * 8];
            #pragma unroll
            for (int nf = 0; nf < 4; nf++)
                b[nf] = *(const h8_t*)&Bs[(wc*64 + nf*16 + (l & 15)) * 64 + ks*32 + (l >> 4) * 8];
            #pragma unroll
            for (int mf = 0; mf < 4; mf++)
                #pragma unroll
                for (int nf = 0; nf < 4; nf++)
                    acc[mf][nf] = __builtin_amdgcn_mfma_f32_16x16x32_f16(
                        a[mf], b[nf], acc[mf][nf], 0, 0, 0);
        }
        __syncthreads();
    }

    // epilogue: dist = xn + en - 2*acc
    // C/D layout (m89-verified): col = lane&15, row = (lane>>4)*4 + reg
    const int cl = l & 15, rh = l >> 4;
    float ecv[4];
    #pragma unroll
    for (int nf = 0; nf < 4; nf++) ecv[nf] = en[n0 + wc*64 + nf*16 + cl];

    #pragma unroll
    for (int mf = 0; mf < 4; mf++) {
        int r0 = m0 + wr*64 + mf*16 + rh*4;
        float x0 = xn[r0], x1 = xn[r0+1], x2 = xn[r0+2], x3 = xn[r0+3];
        #pragma unroll
        for (int nf = 0; nf < 4; nf++) {
            int c = n0 + wc*64 + nf*16 + cl;
            float* dp = &dist[(size_t)r0 * KC + c];
            dp[0]           = x0 + ecv[nf] - 2.0f * acc[mf][nf][0];
            dp[(size_t)KC]  = x1 + ecv[nf] - 2.0f * acc[mf][nf][1];
            dp[(size_t)KC*2]= x2 + ecv[nf] - 2.0f * acc[mf][nf][2];
            dp[(size_t)KC*3]= x3 + ecv[nf] - 2.0f * acc[mf][nf][3];
        }
    }
}

// ---------------------------------------------------------------- top-3
__device__ __forceinline__ bool vi_lt(float v, int i, float u, int j)
{
    return (v < u) || (v == u && i < j);
}

// one wave per row; accumulates the commitment-loss partial per block
__global__ __launch_bounds__(256) void top3_kernel(
    const float* __restrict__ dist, int* __restrict__ idxw,
    float* __restrict__ out_idx, float* __restrict__ counts,
    float* __restrict__ loss_part)
{
    __shared__ float blk_loss;
    if (threadIdx.x == 0) blk_loss = 0.0f;
    __syncthreads();

    int wave = threadIdx.x >> 6;
    int lane = threadIdx.x & 63;
    int row  = blockIdx.x * 4 + wave;   // grid exact: N_ROWS/4 blocks
    const float* dr = dist + (size_t)row * KC;

    float v0 = INFINITY, v1 = INFINITY, v2 = INFINITY;
    int   i0 = 0x7fffffff, i1 = 0x7fffffff, i2 = 0x7fffffff;

    #pragma unroll 4
    for (int it = 0; it < 16; it++) {
        int c = (it * 64 + lane) * 4;
        float4 d = *(const float4*)&dr[c];
        float dv[4] = {d.x, d.y, d.z, d.w};
        #pragma unroll
        for (int q = 0; q < 4; q++) {
            float v = dv[q]; int ci = c + q;
            if (vi_lt(v, ci, v2, i2)) {
                v2 = v; i2 = ci;
                if (vi_lt(v2, i2, v1, i1)) { float tv = v1; int ti = i1; v1 = v2; i1 = i2; v2 = tv; i2 = ti; }
                if (vi_lt(v1, i1, v0, i0)) { float tv = v0; int ti = i0; v0 = v1; i0 = i1; v1 = tv; i1 = ti; }
            }
        }
    }

    #pragma unroll
    for (int off = 1; off < 64; off <<= 1) {
        float u0 = __shfl_xor(v0, off), u1 = __shfl_xor(v1, off), u2 = __shfl_xor(v2, off);
        int   j0 = __shfl_xor(i0, off), j1 = __shfl_xor(i1, off), j2 = __shfl_xor(i2, off);
        float av[3] = {v0, v1, v2}; int ai[3] = {i0, i1, i2};
        float bv[3] = {u0, u1, u2}; int bi[3] = {j0, j1, j2};
        float rv[3]; int ri[3];
        int p = 0, q = 0;
        #pragma unroll
        for (int t = 0; t < 3; t++) {
            bool ta = vi_lt(av[p], ai[p], bv[q], bi[q]);
            rv[t] = ta ? av[p] : bv[q];
            ri[t] = ta ? ai[p] : bi[q];
            p += ta ? 1 : 0; q += ta ? 0 : 1;
        }
        v0 = rv[0]; v1 = rv[1]; v2 = rv[2];
        i0 = ri[0]; i1 = ri[1]; i2 = ri[2];
    }

    if (lane == 0) {
        int base = row * TOPK;
        idxw[base + 0] = i0; idxw[base + 1] = i1; idxw[base + 2] = i2;
        out_idx[base + 0] = (float)i0;
        out_idx[base + 1] = (float)i1;
        out_idx[base + 2] = (float)i2;
        atomicAdd(&counts[i0], 1.0f);
        atomicAdd(&counts[i1], 1.0f);
        atomicAdd(&counts[i2], 1.0f);
        atomicAdd(&blk_loss, v0 + v1 + v2);   // LDS atomic, 4/block
    }
    __syncthreads();
    if (threadIdx.x == 0) loss_part[blockIdx.x] = blk_loss;
}

// -------------------------------------------- pure gather copy: quant = E[idx]
__global__ __launch_bounds__(256) void quant_copy_kernel(
    const int* __restrict__ idxw, const float* __restrict__ E,
    float* __restrict__ quant_out)
{
    int wave = threadIdx.x >> 6;
    int lane = threadIdx.x & 63;
    int j = blockIdx.x * 4 + wave;          // 0 .. N_ROWS*TOPK-1
    int code = idxw[j];
    float4 v = *(const float4*)&E[(size_t)code * DIM + lane * 4];
    *(float4*)&quant_out[(size_t)j * DIM + lane * 4] = v;
}

// ----------------------------------------- K-wise stage 1: avg_probs, sums
__global__ __launch_bounds__(256) void kstage1_kernel(
    const float* __restrict__ counts, const float* __restrict__ ecs,
    float* __restrict__ avgp, float* __restrict__ scalars)
{
    int k = blockIdx.x * 256 + threadIdx.x;
    float cnt = counts[k];
    float pr = ecs[k] * 0.99f + 0.01f * cnt;
    float p = cnt * (1.0f / (float)N_ROWS);
    avgp[k] = p;
    float ent = p * logf(p + 1e-10f);
    int lane = threadIdx.x & 63;
    #pragma unroll
    for (int off = 32; off; off >>= 1) {
        pr  += __shfl_down(pr, off);
        ent += __shfl_down(ent, off);
    }
    if (lane == 0) {
        atomicAdd(&scalars[0], pr);
        atomicAdd(&scalars[2], ent);
    }
}

// ------------------------- K-wise stage 2: normalized new_cs (recomputes pre)
__global__ __launch_bounds__(256) void kstage2_kernel(
    const float* __restrict__ counts, const float* __restrict__ ecs,
    const float* __restrict__ scalars, float* __restrict__ ncs)
{
    int k = blockIdx.x * 256 + threadIdx.x;
    float pre = ecs[k] * 0.99f + 0.01f * counts[k];
    float nt = scalars[0];
    ncs[k] = (pre + 1e-5f) / (nt + (float)KC * 1e-5f) * nt;
}

// ----------------------------------------- prefix scan of counts -> offsets
__global__ __launch_bounds__(1024) void scan_kernel(
    const float* __restrict__ counts, int* __restrict__ offsets)
{
    __shared__ int lds[1024];
    int t = threadIdx.x;
    int c[4]; int s = 0;
    #pragma unroll
    for (int q = 0; q < 4; q++) { c[q] = (int)(counts[t * 4 + q] + 0.5f); s += c[q]; }
    lds[t] = s;
    __syncthreads();
    for (int off = 1; off < 1024; off <<= 1) {
        int v = (t >= off) ? lds[t - off] : 0;
        __syncthreads();
        lds[t] += v;
        __syncthreads();
    }
    int base = lds[t] - s;   // exclusive prefix of this thread's chunk
    offsets[t * 4 + 0] = base;
    offsets[t * 4 + 1] = base + c[0];
    offsets[t * 4 + 2] = base + c[0] + c[1];
    offsets[t * 4 + 3] = base + c[0] + c[1] + c[2];
    if (t == 1023) offsets[4096] = lds[1023];
}

// ----------------------------------------- bucket fill (index atomics only)
__global__ __launch_bounds__(256) void bucket_fill_kernel(
    const int* __restrict__ idxw, const int* __restrict__ offsets,
    int* __restrict__ fill, int* __restrict__ bucket_list)
{
    int j = blockIdx.x * 256 + threadIdx.x;   // grid exact
    int code = idxw[j];
    int pos = atomicAdd(&fill[code], 1);
    bucket_list[offsets[code] + pos] = j / 3;
}

// --------------- per-code segmented sum: dw, new_ema_w, updated_embeddings
__global__ __launch_bounds__(64) void codeupd_kernel(
    const int* __restrict__ offsets, const int* __restrict__ bucket_list,
    const float* __restrict__ flat, const float* __restrict__ emaw,
    const float* __restrict__ ncs, float* __restrict__ nemaw,
    float* __restrict__ upd)
{
    int k = blockIdx.x;
    int lane = threadIdx.x;
    int beg = offsets[k], end = offsets[k + 1];
    float4 acc = {0.0f, 0.0f, 0.0f, 0.0f};
    for (int t = beg; t < end; t++) {
        int n = bucket_list[t];
        float4 v = *(const float4*)&flat[(size_t)n * DIM + lane * 4];
        acc.x += v.x; acc.y += v.y; acc.z += v.z; acc.w += v.w;
    }
    float4 w = *(const float4*)&emaw[(size_t)k * DIM + lane * 4];
    float4 nm;
    nm.x = 0.99f * w.x + 0.01f * acc.x;
    nm.y = 0.99f * w.y + 0.01f * acc.y;
    nm.z = 0.99f * w.z + 0.01f * acc.z;
    nm.w = 0.99f * w.w + 0.01f * acc.w;
    *(float4*)&nemaw[(size_t)k * DIM + lane * 4] = nm;
    float inv = ncs[k];
    float4 u = {nm.x / inv, nm.y / inv, nm.z / inv, nm.w / inv};
    *(float4*)&upd[(size_t)k * DIM + lane * 4] = u;
}

// ------------------------------------------------------------- loss reduce
__global__ __launch_bounds__(1024) void loss_reduce_kernel(
    const float* __restrict__ lp, float* __restrict__ out)
{
    __shared__ float ls[16];
    int t = threadIdx.x;
    float s = lp[t] + lp[t + 1024] + lp[t + 2048] + lp[t + 3072];
    #pragma unroll
    for (int off = 32; off; off >>= 1) s += __shfl_down(s, off);
    if ((t & 63) == 0) ls[t >> 6] = s;
    __syncthreads();
    if (t == 0) {
        float tot = 0.0f;
        #pragma unroll
        for (int i = 0; i < 16; i++) tot += ls[i];
        out[O_LOSS] = 0.25f * tot / (float)(N_ROWS * TOPK * DIM);
    }
}

// ------------------------------------------------------------- perplexity
__global__ void final_kernel(const float* __restrict__ scalars, float* __restrict__ out)
{
    out[O_PERP] = expf(-scalars[2]);
}

extern "C" void kernel_launch(void* const* d_in, const int* in_sizes, int n_in,
                              void* d_out, int out_size, void* d_ws, size_t ws_size,
                              hipStream_t stream)
{
    const float* inputs = (const float*)d_in[0];   // [16,1024,256]
    const float* emb    = (const float*)d_in[1];   // [4096,256]
    const float* ecs    = (const float*)d_in[2];   // [4096]
    const float* emaw   = (const float*)d_in[3];   // [4096,256]
    float* out = (float*)d_out;
    char* ws = (char*)d_ws;

    int*   idxw        = (int*)ws;                  // 49152 ints
    int*   bucket_list = (int*)(ws + 196608);       // 49152 ints
    float* counts      = (float*)(ws + 393216);     // 4096 f
    int*   offsets     = (int*)(ws + 409600);       // 4097 ints
    int*   fill        = (int*)(ws + 430080);       // 4096 ints
    float* xn          = (float*)(ws + 446464);     // 16384 f
    float* en          = (float*)(ws + 512000);     // 4096 f
    float* scalars     = (float*)(ws + 528384);     // 8 f
    float* loss_part   = (float*)(ws + 528448);     // 4096 f

    // fp16 split packs live in the O_QUANT output region (12,582,912 floats,
    // written only by quant_copy_kernel AFTER the GEMM) — no workspace needed.
    // Aq: 16384x768 f16 = 6,291,456 floats @ out+4 (16B aligned)
    // Bq:  4096x768 f16 = 1,572,864 floats @ out+6,291,464 (16B aligned)
    _Float16* Aq = (_Float16*)(out + 4);
    _Float16* Bq = (_Float16*)(out + 6291464);

    hipMemsetAsync(counts, 0, KC * sizeof(float), stream);
    hipMemsetAsync(fill, 0, KC * sizeof(int), stream);
    hipMemsetAsync(scalars, 0, 8 * sizeof(float), stream);

    // fp16 hi/lo split packs
    convert_kernel<<<N_ROWS / 4, 256, 0, stream>>>(inputs, Aq, 512, 256); // [hi|hi|lo]
    convert_kernel<<<KC / 4, 256, 0, stream>>>(emb, Bq, 256, 512);        // [hi|lo|hi]

    rownorm_kernel<<<N_ROWS / 4, 256, 0, stream>>>(inputs, xn, N_ROWS);
    rownorm_kernel<<<KC / 4, 256, 0, stream>>>(emb, en, KC);

    gemm_dist_kernel<<<(N_ROWS / 128) * (KC / 128), 256, 0, stream>>>(
        Aq, Bq, xn, en, out + O_DIST);

    top3_kernel<<<N_ROWS / 4, 256, 0, stream>>>(
        out + O_DIST, idxw, out + O_IDX, counts, loss_part);

    kstage1_kernel<<<KC / 256, 256, 0, stream>>>(counts, ecs, out + O_AVGP, scalars);
    kstage2_kernel<<<KC / 256, 256, 0, stream>>>(counts, ecs, scalars, out + O_NCS);
    scan_kernel<<<1, 1024, 0, stream>>>(counts, offsets);
    bucket_fill_kernel<<<(N_ROWS * TOPK) / 256, 256, 0, stream>>>(
        idxw, offsets, fill, bucket_list);
    codeupd_kernel<<<KC, 64, 0, stream>>>(
        offsets, bucket_list, inputs, emaw, out + O_NCS,
        out + O_NEMAW, out + O_UPD);
    quant_copy_kernel<<<(N_ROWS * TOPK) / 4, 256, 0, stream>>>(
        idxw, emb, out + O_QUANT);

    loss_reduce_kernel<<<1, 1024, 0, stream>>>(loss_part, out);
    final_kernel<<<1, 1, 0, stream>>>(scalars, out);
}

// Round 3
// 723.633 us; speedup vs baseline: 1.5729x; 1.3066x over previous
//
#include <hip/hip_runtime.h>
#include <hip/hip_bf16.h>
#include <math.h>

// Problem constants
#define N_ROWS 16384   // B*T
#define DIM    256
#define KC     4096
#define TOPK   3
#define KSPLIT 768     // [hi|hi|lo] x [hi|lo|hi] fp16-split K
#define TOTAL_E (N_ROWS * TOPK)   // 49152
#define CHUNK 24                  // entries per wave; 49152/24 = 2048 chunks

// Output flat offsets (floats)
#define O_LOSS   0
#define O_QUANT  1
#define O_PERP   12582913
#define O_AVGP   12582914
#define O_IDX    12587010
#define O_DIST   12636162
#define O_NCS    79745026
#define O_NEMAW  79749122
#define O_UPD    80797698

typedef _Float16 h4_t __attribute__((ext_vector_type(4)));
typedef _Float16 h8_t __attribute__((ext_vector_type(8)));
typedef float    f4_t __attribute__((ext_vector_type(4)));

// async global->LDS, 16B per lane, wave-uniform LDS base + lane*16
#define GLL(g, l) __builtin_amdgcn_global_load_lds( \
    (const __attribute__((address_space(1))) unsigned int*)(g), \
    (__attribute__((address_space(3))) unsigned int*)(l), 16, 0, 0)

// ---------------------------------------------------------------- row norms
__global__ __launch_bounds__(256) void rownorm_kernel(
    const float* __restrict__ X, float* __restrict__ out, int rows)
{
    int wave = threadIdx.x >> 6;
    int lane = threadIdx.x & 63;
    int row  = blockIdx.x * 4 + wave;
    if (row >= rows) return;
    float4 v = *(const float4*)&X[(size_t)row * DIM + lane * 4];
    float s = v.x*v.x + v.y*v.y + v.z*v.z + v.w*v.w;
    #pragma unroll
    for (int off = 32; off; off >>= 1) s += __shfl_down(s, off);
    if (lane == 0) out[row] = s;
}

// -------------------------------------------- fp32 -> fp16 hi/lo split pack
// Q row layout (768): A: [hi | hi | lo]  (hi2_off=256, lo_off=512)
//                     B: [hi | lo | hi]  (hi2_off=512, lo_off=256)
__global__ __launch_bounds__(256) void convert_kernel(
    const float* __restrict__ X, _Float16* __restrict__ Q,
    int lo_off, int hi2_off)
{
    int wave = threadIdx.x >> 6;
    int lane = threadIdx.x & 63;
    int row  = blockIdx.x * 4 + wave;          // grid exact
    float4 v = *(const float4*)&X[(size_t)row * DIM + lane * 4];
    h4_t hi, lo;
    hi[0] = (_Float16)v.x; lo[0] = (_Float16)(v.x - (float)hi[0]);
    hi[1] = (_Float16)v.y; lo[1] = (_Float16)(v.y - (float)hi[1]);
    hi[2] = (_Float16)v.z; lo[2] = (_Float16)(v.z - (float)hi[2]);
    hi[3] = (_Float16)v.w; lo[3] = (_Float16)(v.w - (float)hi[3]);
    _Float16* q = Q + (size_t)row * KSPLIT + lane * 4;
    *(h4_t*)(q)           = hi;
    *(h4_t*)(q + hi2_off) = hi;
    *(h4_t*)(q + lo_off)  = lo;
}

// ------------------------------------------------- MFMA GEMM (fp16-split)
// dist[m,n] = xn[m] + en[n] - 2 * dot_f32(X[m,:], E[n,:])
// 128x128 tile, BK=64, 4 waves (2x2), 4x4 frags of 16x16x32 each.
__global__ __launch_bounds__(256) void gemm_dist_kernel(
    const _Float16* __restrict__ Aq,   // [N_ROWS, 768]
    const _Float16* __restrict__ Bq,   // [KC, 768]
    const float* __restrict__ xn,      // [N_ROWS]
    const float* __restrict__ en,      // [KC]
    float* __restrict__ dist)          // [N_ROWS, KC]
{
    __shared__ _Float16 As[128 * 64];
    __shared__ _Float16 Bs[128 * 64];

    // XCD-aware bijective swizzle: nwg=4096, 8 XCDs, 512 per chunk
    int bid = blockIdx.x;
    int swz = (bid & 7) * 512 + (bid >> 3);
    int m0 = (swz >> 5) * 128;     // 128 M-tiles
    int n0 = (swz & 31) * 128;     // 32  N-tiles

    const int tid = threadIdx.x;
    const int w = tid >> 6, l = tid & 63;
    const int wr = w >> 1, wc = w & 1;

    f4_t acc[4][4] = {};

    const int srow = l >> 3;              // 0..7 within 8-row chunk
    const int scol = (l & 7) * 8;         // half offset within row
    const _Float16* Abase = Aq + (size_t)m0 * KSPLIT;
    const _Float16* Bbase = Bq + (size_t)n0 * KSPLIT;

    for (int kt = 0; kt < KSPLIT; kt += 64) {
        #pragma unroll
        for (int i = 0; i < 4; i++) {
            int c = w * 4 + i;            // chunk 0..15, 8 rows each
            int rg = c * 8 + srow;
            GLL(Abase + (size_t)rg * KSPLIT + kt + scol, &As[c * 512]);
            GLL(Bbase + (size_t)rg * KSPLIT + kt + scol, &Bs[c * 512]);
        }
        __syncthreads();                  // drains vmcnt before barrier

        #pragma unroll
        for (int ks = 0; ks < 2; ks++) {
            h8_t a[4], b[4];
            #pragma unroll
            for (int mf = 0; mf < 4; mf++)
                a[mf] = *(const h8_t*)&As[(wr*64 + mf*16 + (l & 15)) * 64 + ks*32 + (l >> 4) * 8];
            #pragma unroll
            for (int nf = 0; nf < 4; nf++)
                b[nf] = *(const h8_t*)&Bs[(wc*64 + nf*16 + (l & 15)) * 64 + ks*32 + (l >> 4) * 8];
            #pragma unroll
            for (int mf = 0; mf < 4; mf++)
                #pragma unroll
                for (int nf = 0; nf < 4; nf++)
                    acc[mf][nf] = __builtin_amdgcn_mfma_f32_16x16x32_f16(
                        a[mf], b[nf], acc[mf][nf], 0, 0, 0);
        }
        __syncthreads();
    }

    // epilogue: dist = xn + en - 2*acc
    // C/D layout (m89-verified): col = lane&15, row = (lane>>4)*4 + reg
    const int cl = l & 15, rh = l >> 4;
    float ecv[4];
    #pragma unroll
    for (int nf = 0; nf < 4; nf++) ecv[nf] = en[n0 + wc*64 + nf*16 + cl];

    #pragma unroll
    for (int mf = 0; mf < 4; mf++) {
        int r0 = m0 + wr*64 + mf*16 + rh*4;
        float x0 = xn[r0], x1 = xn[r0+1], x2 = xn[r0+2], x3 = xn[r0+3];
        #pragma unroll
        for (int nf = 0; nf < 4; nf++) {
            int c = n0 + wc*64 + nf*16 + cl;
            float* dp = &dist[(size_t)r0 * KC + c];
            dp[0]           = x0 + ecv[nf] - 2.0f * acc[mf][nf][0];
            dp[(size_t)KC]  = x1 + ecv[nf] - 2.0f * acc[mf][nf][1];
            dp[(size_t)KC*2]= x2 + ecv[nf] - 2.0f * acc[mf][nf][2];
            dp[(size_t)KC*3]= x3 + ecv[nf] - 2.0f * acc[mf][nf][3];
        }
    }
}

// ---------------------------------------------------------------- top-3
__device__ __forceinline__ bool vi_lt(float v, int i, float u, int j)
{
    return (v < u) || (v == u && i < j);
}

// one wave per row; accumulates the commitment-loss partial per block
__global__ __launch_bounds__(256) void top3_kernel(
    const float* __restrict__ dist, int* __restrict__ idxw,
    float* __restrict__ out_idx, float* __restrict__ counts,
    float* __restrict__ loss_part)
{
    __shared__ float blk_loss;
    if (threadIdx.x == 0) blk_loss = 0.0f;
    __syncthreads();

    int wave = threadIdx.x >> 6;
    int lane = threadIdx.x & 63;
    int row  = blockIdx.x * 4 + wave;   // grid exact: N_ROWS/4 blocks
    const float* dr = dist + (size_t)row * KC;

    float v0 = INFINITY, v1 = INFINITY, v2 = INFINITY;
    int   i0 = 0x7fffffff, i1 = 0x7fffffff, i2 = 0x7fffffff;

    #pragma unroll 4
    for (int it = 0; it < 16; it++) {
        int c = (it * 64 + lane) * 4;
        float4 d = *(const float4*)&dr[c];
        float dv[4] = {d.x, d.y, d.z, d.w};
        #pragma unroll
        for (int q = 0; q < 4; q++) {
            float v = dv[q]; int ci = c + q;
            if (vi_lt(v, ci, v2, i2)) {
                v2 = v; i2 = ci;
                if (vi_lt(v2, i2, v1, i1)) { float tv = v1; int ti = i1; v1 = v2; i1 = i2; v2 = tv; i2 = ti; }
                if (vi_lt(v1, i1, v0, i0)) { float tv = v0; int ti = i0; v0 = v1; i0 = i1; v1 = tv; i1 = ti; }
            }
        }
    }

    #pragma unroll
    for (int off = 1; off < 64; off <<= 1) {
        float u0 = __shfl_xor(v0, off), u1 = __shfl_xor(v1, off), u2 = __shfl_xor(v2, off);
        int   j0 = __shfl_xor(i0, off), j1 = __shfl_xor(i1, off), j2 = __shfl_xor(i2, off);
        float av[3] = {v0, v1, v2}; int ai[3] = {i0, i1, i2};
        float bv[3] = {u0, u1, u2}; int bi[3] = {j0, j1, j2};
        float rv[3]; int ri[3];
        int p = 0, q = 0;
        #pragma unroll
        for (int t = 0; t < 3; t++) {
            bool ta = vi_lt(av[p], ai[p], bv[q], bi[q]);
            rv[t] = ta ? av[p] : bv[q];
            ri[t] = ta ? ai[p] : bi[q];
            p += ta ? 1 : 0; q += ta ? 0 : 1;
        }
        v0 = rv[0]; v1 = rv[1]; v2 = rv[2];
        i0 = ri[0]; i1 = ri[1]; i2 = ri[2];
    }

    if (lane == 0) {
        int base = row * TOPK;
        idxw[base + 0] = i0; idxw[base + 1] = i1; idxw[base + 2] = i2;
        out_idx[base + 0] = (float)i0;
        out_idx[base + 1] = (float)i1;
        out_idx[base + 2] = (float)i2;
        atomicAdd(&counts[i0], 1.0f);
        atomicAdd(&counts[i1], 1.0f);
        atomicAdd(&counts[i2], 1.0f);
        atomicAdd(&blk_loss, v0 + v1 + v2);   // LDS atomic, 4/block
    }
    __syncthreads();
    if (threadIdx.x == 0) loss_part[blockIdx.x] = blk_loss;
}

// -------------------------------------------- pure gather copy: quant = E[idx]
__global__ __launch_bounds__(256) void quant_copy_kernel(
    const int* __restrict__ idxw, const float* __restrict__ E,
    float* __restrict__ quant_out)
{
    int wave = threadIdx.x >> 6;
    int lane = threadIdx.x & 63;
    int j = blockIdx.x * 4 + wave;          // 0 .. N_ROWS*TOPK-1
    int code = idxw[j];
    float4 v = *(const float4*)&E[(size_t)code * DIM + lane * 4];
    *(float4*)&quant_out[(size_t)j * DIM + lane * 4] = v;
}

// ----------------------------------------- K-wise stage 1: avg_probs, sums
__global__ __launch_bounds__(256) void kstage1_kernel(
    const float* __restrict__ counts, const float* __restrict__ ecs,
    float* __restrict__ avgp, float* __restrict__ scalars)
{
    int k = blockIdx.x * 256 + threadIdx.x;
    float cnt = counts[k];
    float pr = ecs[k] * 0.99f + 0.01f * cnt;
    float p = cnt * (1.0f / (float)N_ROWS);
    avgp[k] = p;
    float ent = p * logf(p + 1e-10f);
    int lane = threadIdx.x & 63;
    #pragma unroll
    for (int off = 32; off; off >>= 1) {
        pr  += __shfl_down(pr, off);
        ent += __shfl_down(ent, off);
    }
    if (lane == 0) {
        atomicAdd(&scalars[0], pr);
        atomicAdd(&scalars[2], ent);
    }
}

// ------------------------- K-wise stage 2: normalized new_cs (recomputes pre)
__global__ __launch_bounds__(256) void kstage2_kernel(
    const float* __restrict__ counts, const float* __restrict__ ecs,
    const float* __restrict__ scalars, float* __restrict__ ncs)
{
    int k = blockIdx.x * 256 + threadIdx.x;
    float pre = ecs[k] * 0.99f + 0.01f * counts[k];
    float nt = scalars[0];
    ncs[k] = (pre + 1e-5f) / (nt + (float)KC * 1e-5f) * nt;
}

// ----------------------------------------- prefix scan of counts -> offsets
__global__ __launch_bounds__(1024) void scan_kernel(
    const float* __restrict__ counts, int* __restrict__ offsets)
{
    __shared__ int lds[1024];
    int t = threadIdx.x;
    int c[4]; int s = 0;
    #pragma unroll
    for (int q = 0; q < 4; q++) { c[q] = (int)(counts[t * 4 + q] + 0.5f); s += c[q]; }
    lds[t] = s;
    __syncthreads();
    for (int off = 1; off < 1024; off <<= 1) {
        int v = (t >= off) ? lds[t - off] : 0;
        __syncthreads();
        lds[t] += v;
        __syncthreads();
    }
    int base = lds[t] - s;   // exclusive prefix of this thread's chunk
    offsets[t * 4 + 0] = base;
    offsets[t * 4 + 1] = base + c[0];
    offsets[t * 4 + 2] = base + c[0] + c[1];
    offsets[t * 4 + 3] = base + c[0] + c[1] + c[2];
    if (t == 1023) offsets[4096] = lds[1023];
}

// -------------------- bucket fill: packed (code<<14 | row), grouped by code
__global__ __launch_bounds__(256) void bucket_fill_kernel(
    const int* __restrict__ idxw, const int* __restrict__ offsets,
    int* __restrict__ fill, int* __restrict__ bucket_list)
{
    int j = blockIdx.x * 256 + threadIdx.x;   // grid exact
    int code = idxw[j];
    int pos = atomicAdd(&fill[code], 1);
    bucket_list[offsets[code] + pos] = (code << 14) | (j / 3);
}

// -------------- balanced gather-accumulate: dw[code] += flat[row] over chunks
// One wave per CHUNK entries (uniform work, no straggler codes). Run flushes
// to dw via atomicAdd on code-change; dw pre-zeroed.
__global__ __launch_bounds__(256) void codeacc_kernel(
    const int* __restrict__ bl, const float* __restrict__ flat,
    float* __restrict__ dw)
{
    int wave = threadIdx.x >> 6;
    int lane = threadIdx.x & 63;
    int chunk = blockIdx.x * 4 + wave;        // 2048 chunks, grid exact
    int beg = chunk * CHUNK;

    // prefetch packed entries (independent loads, all in flight)
    int ent[CHUNK];
    #pragma unroll
    for (int q = 0; q < CHUNK; q++) ent[q] = bl[beg + q];

    float4 acc = {0.0f, 0.0f, 0.0f, 0.0f};
    int prev = ent[0] >> 14;
    #pragma unroll
    for (int q = 0; q < CHUNK; q++) {
        int code = ent[q] >> 14;
        int n    = ent[q] & 0x3fff;
        if (code != prev) {
            float* p = &dw[(size_t)prev * DIM + lane * 4];
            atomicAdd(p + 0, acc.x); atomicAdd(p + 1, acc.y);
            atomicAdd(p + 2, acc.z); atomicAdd(p + 3, acc.w);
            acc.x = acc.y = acc.z = acc.w = 0.0f;
            prev = code;
        }
        float4 v = *(const float4*)&flat[(size_t)n * DIM + lane * 4];
        acc.x += v.x; acc.y += v.y; acc.z += v.z; acc.w += v.w;
    }
    float* p = &dw[(size_t)prev * DIM + lane * 4];
    atomicAdd(p + 0, acc.x); atomicAdd(p + 1, acc.y);
    atomicAdd(p + 2, acc.z); atomicAdd(p + 3, acc.w);
}

// ------------- finalize: nemaw = 0.99*emaw + 0.01*dw ; upd = nemaw / ncs
__global__ __launch_bounds__(256) void finalize_kernel(
    const float* __restrict__ dw, const float* __restrict__ emaw,
    const float* __restrict__ ncs, float* __restrict__ nemaw,
    float* __restrict__ upd)
{
    int wave = threadIdx.x >> 6;
    int lane = threadIdx.x & 63;
    int k = blockIdx.x * 4 + wave;            // 1024 blocks, grid exact
    size_t o = (size_t)k * DIM + lane * 4;
    float4 d = *(const float4*)&dw[o];
    float4 w = *(const float4*)&emaw[o];
    float4 nm;
    nm.x = 0.99f * w.x + 0.01f * d.x;
    nm.y = 0.99f * w.y + 0.01f * d.y;
    nm.z = 0.99f * w.z + 0.01f * d.z;
    nm.w = 0.99f * w.w + 0.01f * d.w;
    *(float4*)&nemaw[o] = nm;
    float inv = ncs[k];
    float4 u = {nm.x / inv, nm.y / inv, nm.z / inv, nm.w / inv};
    *(float4*)&upd[o] = u;
}

// ------------------------------------------------------------- loss reduce
__global__ __launch_bounds__(1024) void loss_reduce_kernel(
    const float* __restrict__ lp, float* __restrict__ out)
{
    __shared__ float ls[16];
    int t = threadIdx.x;
    float s = lp[t] + lp[t + 1024] + lp[t + 2048] + lp[t + 3072];
    #pragma unroll
    for (int off = 32; off; off >>= 1) s += __shfl_down(s, off);
    if ((t & 63) == 0) ls[t >> 6] = s;
    __syncthreads();
    if (t == 0) {
        float tot = 0.0f;
        #pragma unroll
        for (int i = 0; i < 16; i++) tot += ls[i];
        out[O_LOSS] = 0.25f * tot / (float)(N_ROWS * TOPK * DIM);
    }
}

// ------------------------------------------------------------- perplexity
__global__ void final_kernel(const float* __restrict__ scalars, float* __restrict__ out)
{
    out[O_PERP] = expf(-scalars[2]);
}

extern "C" void kernel_launch(void* const* d_in, const int* in_sizes, int n_in,
                              void* d_out, int out_size, void* d_ws, size_t ws_size,
                              hipStream_t stream)
{
    const float* inputs = (const float*)d_in[0];   // [16,1024,256]
    const float* emb    = (const float*)d_in[1];   // [4096,256]
    const float* ecs    = (const float*)d_in[2];   // [4096]
    const float* emaw   = (const float*)d_in[3];   // [4096,256]
    float* out = (float*)d_out;
    char* ws = (char*)d_ws;

    int*   idxw        = (int*)ws;                  // 49152 ints
    int*   bucket_list = (int*)(ws + 196608);       // 49152 ints
    float* counts      = (float*)(ws + 393216);     // 4096 f
    int*   offsets     = (int*)(ws + 409600);       // 4097 ints
    int*   fill        = (int*)(ws + 430080);       // 4096 ints
    float* xn          = (float*)(ws + 446464);     // 16384 f
    float* en          = (float*)(ws + 512000);     // 4096 f
    float* scalars     = (float*)(ws + 528384);     // 8 f
    float* loss_part   = (float*)(ws + 528448);     // 4096 f

    // Scratch in the O_QUANT output region (free until quant_copy_kernel):
    // Aq: 16384x768 f16 = 6,291,456 floats @ out+4
    // Bq:  4096x768 f16 = 1,572,864 floats @ out+6,291,464
    // dw:  4096x256 f32 = 1,048,576 floats @ out+8,000,000
    _Float16* Aq = (_Float16*)(out + 4);
    _Float16* Bq = (_Float16*)(out + 6291464);
    float*    dw = out + 8000000;

    hipMemsetAsync(counts, 0, KC * sizeof(float), stream);
    hipMemsetAsync(fill, 0, KC * sizeof(int), stream);
    hipMemsetAsync(scalars, 0, 8 * sizeof(float), stream);
    hipMemsetAsync(dw, 0, KC * DIM * sizeof(float), stream);

    // fp16 hi/lo split packs
    convert_kernel<<<N_ROWS / 4, 256, 0, stream>>>(inputs, Aq, 512, 256); // [hi|hi|lo]
    convert_kernel<<<KC / 4, 256, 0, stream>>>(emb, Bq, 256, 512);        // [hi|lo|hi]

    rownorm_kernel<<<N_ROWS / 4, 256, 0, stream>>>(inputs, xn, N_ROWS);
    rownorm_kernel<<<KC / 4, 256, 0, stream>>>(emb, en, KC);

    gemm_dist_kernel<<<(N_ROWS / 128) * (KC / 128), 256, 0, stream>>>(
        Aq, Bq, xn, en, out + O_DIST);

    top3_kernel<<<N_ROWS / 4, 256, 0, stream>>>(
        out + O_DIST, idxw, out + O_IDX, counts, loss_part);

    kstage1_kernel<<<KC / 256, 256, 0, stream>>>(counts, ecs, out + O_AVGP, scalars);
    kstage2_kernel<<<KC / 256, 256, 0, stream>>>(counts, ecs, scalars, out + O_NCS);
    scan_kernel<<<1, 1024, 0, stream>>>(counts, offsets);
    bucket_fill_kernel<<<(N_ROWS * TOPK) / 256, 256, 0, stream>>>(
        idxw, offsets, fill, bucket_list);

    codeacc_kernel<<<(TOTAL_E / CHUNK) / 4, 256, 0, stream>>>(
        bucket_list, inputs, dw);
    finalize_kernel<<<KC / 4, 256, 0, stream>>>(
        dw, emaw, out + O_NCS, out + O_NEMAW, out + O_UPD);

    quant_copy_kernel<<<(N_ROWS * TOPK) / 4, 256, 0, stream>>>(
        idxw, emb, out + O_QUANT);

    loss_reduce_kernel<<<1, 1024, 0, stream>>>(loss_part, out);
    final_kernel<<<1, 1, 0, stream>>>(scalars, out);
}